// Round 14
// baseline (203.095 us; speedup 1.0000x reference)
//
#include <hip/hip_runtime.h>

namespace {

constexpr int N_ENTITY = 50000;
constexpr int NR2      = 1000;     // 2 * num_relations
constexpr int NE       = 600000;
constexpr int D        = 128;
constexpr int BCAP     = 16384;    // coarse-bucket capacity (mean ~12.3K, +36 sigma)
constexpr float BN_EPS = 1e-5f;

constexpr int NB_BIN   = (NE + 4095) / 4096;   // 147 bin blocks (4096 edges, 16/thread)
constexpr int NB_PREP  = 89;                   // prep blocks (64 transpose + 1 slw + 24 pack)
constexpr int NB_GEMM  = (N_ENTITY + 63) / 64; // 782 gemm blocks
constexpr int NB_XR    = NR2 / 8;              // 125 xr blocks

// ---- workspace layout (units of 4 bytes) ----
constexpr size_t OFF_YF   = 0;                     // 1,600,000 (fp8 x4 per u32)
constexpr size_t OFF_YB   = OFF_YF + 1600000;      // 1,600,000
constexpr size_t OFF_YL   = OFF_YB + 1600000;      // 3,200,000 (bf16 pairs)
constexpr size_t OFF_ZF   = OFF_YL + 3200000;      // 32,000 (fp8)
constexpr size_t OFF_ZB   = OFF_ZF + 32000;        // 32,000
constexpr size_t OFF_WPK  = OFF_ZB + 32000;        // 24,576
constexpr size_t OFF_WRT  = OFF_WPK + 24576;       // 16,384
constexpr size_t OFF_SLW  = OFF_WRT + 16384;       // 256
constexpr size_t OFF_DEG0 = OFF_SLW + 256;         // 50,048
constexpr size_t OFF_DEG1 = OFF_DEG0 + 50048;      // 50,048
constexpr size_t OFF_OFF0 = OFF_DEG1 + 50048;      // 50,048
constexpr size_t OFF_OFF1 = OFF_OFF0 + 50048;      // 50,048
constexpr size_t OFF_RDG0 = OFF_OFF1 + 50048;      // 50,048 f32
constexpr size_t OFF_RDG1 = OFF_RDG0 + 50048;      // 50,048 f32
constexpr size_t OFF_GCNT = OFF_RDG1 + 50048;      // 128
constexpr size_t OFF_BIN0 = OFF_GCNT + 128;        // 2,097,152 (uint2 x 64x16384)
constexpr size_t OFF_BIN1 = OFF_BIN0 + 2097152;    // 2,097,152
constexpr size_t OFF_EL0  = OFF_BIN1 + 2097152;    // 1,048,576 u32
constexpr size_t OFF_EL1  = OFF_EL0 + 1048576;     // 1,048,576
constexpr size_t OFF_PART = OFF_EL1 + 1048576;     // 65,536
constexpr size_t OFF_KSH  = OFF_PART + 65536;      // 256
// total ~13.16M u32 = 52.7 MB

} // namespace

typedef __attribute__((ext_vector_type(8))) short bf16x8;
typedef __attribute__((ext_vector_type(4))) float f32x4;
typedef __attribute__((ext_vector_type(2))) float f32x2;

__device__ inline unsigned f2bf(float x) {
  unsigned u = __float_as_uint(x);
  return (u + 0x7FFFu + ((u >> 16) & 1u)) >> 16;   // RNE
}
__device__ inline unsigned pack2bf(float a, float b) { return f2bf(a) | (f2bf(b) << 16); }
__device__ inline float bflo(unsigned v) { return __uint_as_float(v << 16); }
__device__ inline float bfhi(unsigned v) { return __uint_as_float(v & 0xFFFF0000u); }

// ---------------- k_prep: w_rel transpose + self_loop@w_loop + weight frag-pack ----------------
__global__ __launch_bounds__(256) void k_prep(
    const float* __restrict__ wl, const float* __restrict__ wf,
    const float* __restrict__ wb, const float* __restrict__ wrel,
    const float* __restrict__ sl,
    unsigned* __restrict__ wpk, float* __restrict__ wrT, float* __restrict__ slw) {
  const int b = blockIdx.x;
  const int t = threadIdx.x;
  if (b < 64) {
    int i = b * 256 + t;
    wrT[(i & 127) * D + (i >> 7)] = wrel[i];
  } else if (b == 64) {
    if (t < 128) {
      float a = 0.f;
      for (int k = 0; k < D; ++k) a = fmaf(sl[k], wl[k * D + t], a);
      slw[t] = a;
    }
  } else {
    int idx = (b - 65) * 256 + t;   // < 6144
    int w = idx / 2048, rem = idx % 2048;
    int frag = rem / 64, l = rem % 64;
    int ct = frag >> 2, kf = frag & 3;
    const float* W = (w == 0) ? wl : (w == 1) ? wf : wb;
    int krow = kf * 32 + (l >> 4) * 8;
    int col = ct * 16 + (l & 15);
    unsigned base = (unsigned)(w * 8192 + (frag * 64 + l) * 4);
#pragma unroll
    for (int j = 0; j < 8; j += 2) {
      float a = W[(krow + j) * D + col];
      float bb = W[(krow + j + 1) * D + col];
      wpk[base + (j >> 1)] = pack2bf(a, bb);
    }
  }
}

// ---------------- k_mid (fused): coarse bin ∥ MFMA GEMM ∥ x_r GEMM ----------------
// blocks [0,NB_BIN): bin; [NB_BIN,+NB_GEMM): gemm; then NB_XR xr blocks.
// All three are mutually independent (gemm/xr need only wpk/wrT/slw from k_prep).
__global__ __launch_bounds__(256) void k_mid(
    // bin part
    const int* __restrict__ esrc, const int* __restrict__ etgt,
    const int* __restrict__ etype, unsigned* __restrict__ gcnt,
    uint2* __restrict__ bin0, uint2* __restrict__ bin1,
    // gemm part
    const float* __restrict__ xe, const unsigned* __restrict__ wpk,
    const float* __restrict__ slw, unsigned* __restrict__ Yl,
    unsigned* __restrict__ Yf, unsigned* __restrict__ Yb,
    // xr part
    const float* __restrict__ xr, const float* __restrict__ wf,
    const float* __restrict__ wb, const float* __restrict__ wrT,
    unsigned* __restrict__ Zf, unsigned* __restrict__ Zb, float* __restrict__ xrnew) {
  __shared__ float smem[64 * 140];   // 35.8 KB, shared by all paths
  const int tid = threadIdx.x;

  if (blockIdx.x < NB_BIN) {
    // ---- coarse binning: 4096 edges/block (16/thread) ----
    unsigned* cnt  = (unsigned*)smem;        // 128
    unsigned* base = cnt + 128;              // 128
    if (tid < 128) cnt[tid] = 0;
    __syncthreads();
    const int start = blockIdx.x * 4096;
    int sv[16], tv[16];
#pragma unroll
    for (int k = 0; k < 16; ++k) {
      int i = start + k * 256 + tid;
      if (i < NE) {
        sv[k] = esrc[i]; tv[k] = etgt[i];
        atomicAdd(&cnt[(unsigned)sv[k] >> 10], 1u);
        atomicAdd(&cnt[64 + ((unsigned)tv[k] >> 10)], 1u);
      } else {
        sv[k] = -1; tv[k] = -1;
      }
    }
    __syncthreads();
    if (tid < 128) {
      base[tid] = atomicAdd(&gcnt[tid], cnt[tid]);
      cnt[tid] = 0;
    }
    __syncthreads();
#pragma unroll
    for (int k = 0; k < 16; ++k) {
      int i = start + k * 256 + tid;
      if (i < NE) {
        int s = sv[k], t = tv[k], et = etype[i];
        unsigned b0 = (unsigned)s >> 10, b1 = (unsigned)t >> 10;
        unsigned r0 = atomicAdd(&cnt[b0], 1u);
        unsigned p0 = base[b0] + r0;
        if (p0 < (unsigned)BCAP)
          bin0[(size_t)b0 * BCAP + p0] =
              make_uint2(((unsigned)s << 16) | (unsigned)t, (unsigned)(2 * et + 1));
        unsigned r1 = atomicAdd(&cnt[64 + b1], 1u);
        unsigned p1 = base[64 + b1] + r1;
        if (p1 < (unsigned)BCAP)
          bin1[(size_t)b1 * BCAP + p1] =
              make_uint2(((unsigned)t << 16) | (unsigned)s, (unsigned)(2 * et));
      }
    }
    return;
  }

  if (blockIdx.x < NB_BIN + NB_GEMM) {
    // ---- big GEMM: xe read once; Yl bf16 (slw pre-subtracted); Yf/Yb fp8 ----
    const int wv = tid >> 6, l = tid & 63;
    const int tile = (blockIdx.x - NB_BIN) * 64;
    const int arow = tile + wv * 16 + (l & 15);
    const int arc = (arow < N_ENTITY) ? arow : (N_ENTITY - 1);
    const int kbase = (l >> 4) * 8;
    bf16x8 a[4];
#pragma unroll
    for (int kf = 0; kf < 4; ++kf) {
      const float* src = xe + (size_t)arc * D + kf * 32 + kbase;
      float4 lo = *(const float4*)(src);
      float4 hi = *(const float4*)(src + 4);
      union { bf16x8 v; unsigned u[4]; } cv;
      cv.u[0] = pack2bf(lo.x, lo.y);
      cv.u[1] = pack2bf(lo.z, lo.w);
      cv.u[2] = pack2bf(hi.x, hi.y);
      cv.u[3] = pack2bf(hi.z, hi.w);
      a[kf] = cv.v;
    }
    for (int widx = 0; widx < 3; ++widx) {
      const unsigned* wbase = wpk + widx * 8192;
#pragma unroll
      for (int ct = 0; ct < 8; ++ct) {
        f32x4 acc = {0.f, 0.f, 0.f, 0.f};
#pragma unroll
        for (int kf = 0; kf < 4; ++kf) {
          const bf16x8 b = *(const bf16x8*)(wbase + ((ct * 4 + kf) * 64 + l) * 4);
          acc = __builtin_amdgcn_mfma_f32_16x16x32_bf16(a[kf], b, acc, 0, 0, 0);
        }
        const int rbase = wv * 16 + (l >> 4) * 4;
        const int cc = ct * 16 + (l & 15);
#pragma unroll
        for (int j = 0; j < 4; ++j) smem[(rbase + j) * 140 + cc] = acc[j];
      }
      __syncthreads();
      for (int f = tid; f < 64 * 32; f += 256) {
        int row = f >> 5, c4 = (f & 31) * 4;
        int g = tile + row;
        if (g < N_ENTITY) {
          float4 v = *(float4*)(smem + row * 140 + c4);
          if (widx == 0) {
            float4 s = *(const float4*)(slw + c4);
            uint2 p = make_uint2(pack2bf(v.x - s.x, v.y - s.y),
                                 pack2bf(v.z - s.z, v.w - s.w));
            *(uint2*)(Yl + (size_t)g * 64 + (c4 >> 1)) = p;
          } else {
            int p = __builtin_amdgcn_cvt_pk_fp8_f32(v.x, v.y, 0, false);
            p = __builtin_amdgcn_cvt_pk_fp8_f32(v.z, v.w, p, true);
            unsigned* dst = ((widx == 1) ? Yf : Yb);
            dst[(size_t)g * 32 + (c4 >> 2)] = (unsigned)p;
          }
        }
      }
      __syncthreads();
    }
    return;
  }

  // ---- x_r @ {w_fwd, w_bwd, w_rel^T}: Zf/Zb fp8, xrnew f32 ----
  float* xs = smem;
  const int tile = (blockIdx.x - NB_BIN - NB_GEMM) * 8;
  for (int f = tid * 4; f < 8 * 128; f += 1024) {
    int rr = f >> 7, kk = f & 127;
    *(float4*)(xs + rr * 132 + kk) = *(const float4*)(xr + (size_t)(tile + rr) * D + kk);
  }
  __syncthreads();
  const int c4 = (tid & 31) * 4;
  const int rs = tid >> 5;
  const int row = tile + rs;
  float4 af = make_float4(0, 0, 0, 0), ab = make_float4(0, 0, 0, 0), ar = make_float4(0, 0, 0, 0);
#pragma unroll 4
  for (int k = 0; k < 128; ++k) {
    float x = xs[rs * 132 + k];
    float4 f4 = *(const float4*)(wf + k * D + c4);
    float4 b4 = *(const float4*)(wb + k * D + c4);
    float4 r4 = *(const float4*)(wrT + k * D + c4);
    af.x = fmaf(x, f4.x, af.x); af.y = fmaf(x, f4.y, af.y);
    af.z = fmaf(x, f4.z, af.z); af.w = fmaf(x, f4.w, af.w);
    ab.x = fmaf(x, b4.x, ab.x); ab.y = fmaf(x, b4.y, ab.y);
    ab.z = fmaf(x, b4.z, ab.z); ab.w = fmaf(x, b4.w, ab.w);
    ar.x = fmaf(x, r4.x, ar.x); ar.y = fmaf(x, r4.y, ar.y);
    ar.z = fmaf(x, r4.z, ar.z); ar.w = fmaf(x, r4.w, ar.w);
  }
  int pf = __builtin_amdgcn_cvt_pk_fp8_f32(af.x, af.y, 0, false);
  pf = __builtin_amdgcn_cvt_pk_fp8_f32(af.z, af.w, pf, true);
  int pb = __builtin_amdgcn_cvt_pk_fp8_f32(ab.x, ab.y, 0, false);
  pb = __builtin_amdgcn_cvt_pk_fp8_f32(ab.z, ab.w, pb, true);
  Zf[(size_t)row * 32 + (c4 >> 2)] = (unsigned)pf;
  Zb[(size_t)row * 32 + (c4 >> 2)] = (unsigned)pb;
  *(float4*)(xrnew + (size_t)row * D + c4) = ar;
}

// ---------------- k_bucket: per-bucket fine CSR ----------------
__global__ __launch_bounds__(256) void k_bucket(
    const uint2* __restrict__ bin0, const uint2* __restrict__ bin1,
    const unsigned* __restrict__ gcnt,
    unsigned* __restrict__ deg0, unsigned* __restrict__ deg1,
    unsigned* __restrict__ off0, unsigned* __restrict__ off1,
    float* __restrict__ rdeg0, float* __restrict__ rdeg1,
    unsigned* __restrict__ el0, unsigned* __restrict__ el1) {
  __shared__ unsigned hist[1024], excl[1024];
  __shared__ unsigned wtot[4], wof[4];
  const int tid = threadIdx.x;
  const int bb = blockIdx.x & 63, dd = blockIdx.x >> 6;
  const uint2* bin = dd ? bin1 : bin0;
  unsigned* deg = dd ? deg1 : deg0;
  unsigned* off = dd ? off1 : off0;
  float* rdeg = dd ? rdeg1 : rdeg0;
  unsigned* el = dd ? el1 : el0;
  const int n0 = bb << 10;
  unsigned m = gcnt[dd * 64 + bb];
  if (m > (unsigned)BCAP) m = (unsigned)BCAP;
  const uint2* src = bin + (size_t)bb * BCAP;

#pragma unroll
  for (int k = 0; k < 4; ++k) hist[tid * 4 + k] = 0;
  __syncthreads();
  for (unsigned j = tid; j < m; j += 256) {
    unsigned n = src[j].x >> 16;
    atomicAdd(&hist[n - n0], 1u);
  }
  __syncthreads();
  unsigned h0 = hist[tid * 4], h1 = hist[tid * 4 + 1];
  unsigned h2 = hist[tid * 4 + 2], h3 = hist[tid * 4 + 3];
  unsigned ts = h0 + h1 + h2 + h3;
  unsigned incl = ts;
  const int lane = tid & 63, wid = tid >> 6;
#pragma unroll
  for (int dsh = 1; dsh < 64; dsh <<= 1) {
    unsigned nv = __shfl_up(incl, dsh, 64);
    if (lane >= dsh) incl += nv;
  }
  if (lane == 63) wtot[wid] = incl;
  __syncthreads();
  if (tid == 0) {
    unsigned a = 0;
    for (int w = 0; w < 4; ++w) { wof[w] = a; a += wtot[w]; }
  }
  __syncthreads();
  unsigned ex = wof[wid] + incl - ts;
  excl[tid * 4] = ex;
  excl[tid * 4 + 1] = ex + h0;
  excl[tid * 4 + 2] = ex + h0 + h1;
  excl[tid * 4 + 3] = ex + h0 + h1 + h2;
  const unsigned bstart = (unsigned)bb * BCAP;
#pragma unroll
  for (int k = 0; k < 4; ++k) {
    int idx = tid * 4 + k;
    int n = n0 + idx;
    if (n < N_ENTITY) {
      unsigned dv = hist[idx];
      deg[n] = dv;
      off[n] = bstart + excl[idx];
      rdeg[n] = rsqrtf((float)dv);
    }
  }
  __syncthreads();
#pragma unroll
  for (int k = 0; k < 4; ++k) hist[tid * 4 + k] = 0;
  __syncthreads();
  for (unsigned j = tid; j < m; j += 256) {
    uint2 e = src[j];
    unsigned li = (e.x >> 16) - (unsigned)n0;
    unsigned other = e.x & 0xFFFFu;
    unsigned r = atomicAdd(&hist[li], 1u);
    el[bstart + excl[li] + r] = (other << 10) | e.y;
  }
}

// ---------------- per-entity edge aggregation: edge-pair vectorized ----------------
__device__ inline void pstep(const unsigned* __restrict__ Y, const unsigned* __restrict__ Z,
                             unsigned d, float rw, int i, int half, int col, float4& acc) {
  int e = i + half;
  unsigned pk = __shfl(d, e, 64);
  float w = __shfl(rw, e, 64);
  unsigned yv = Y[(size_t)(pk >> 10) * 32 + col];
  unsigned zv = Z[(size_t)(pk & 1023u) * 32 + col];
  f32x2 ylo = __builtin_amdgcn_cvt_pk_f32_fp8((int)yv, false);
  f32x2 yhi = __builtin_amdgcn_cvt_pk_f32_fp8((int)yv, true);
  f32x2 zlo = __builtin_amdgcn_cvt_pk_f32_fp8((int)zv, false);
  f32x2 zhi = __builtin_amdgcn_cvt_pk_f32_fp8((int)zv, true);
  acc.x = fmaf(w, ylo.x - zlo.x, acc.x);
  acc.y = fmaf(w, ylo.y - zlo.y, acc.y);
  acc.z = fmaf(w, yhi.x - zhi.x, acc.z);
  acc.w = fmaf(w, yhi.y - zhi.y, acc.w);
}

__global__ __launch_bounds__(256) void k_gather(
    const unsigned* __restrict__ Yl,
    const unsigned* __restrict__ Yf, const unsigned* __restrict__ Yb,
    const unsigned* __restrict__ Zf, const unsigned* __restrict__ Zb,
    const unsigned* __restrict__ deg0, const unsigned* __restrict__ deg1,
    const unsigned* __restrict__ off0, const unsigned* __restrict__ off1,
    const float* __restrict__ rdeg0, const float* __restrict__ rdeg1,
    const unsigned* __restrict__ el0, const unsigned* __restrict__ el1,
    float* __restrict__ out) {
  const int lane = threadIdx.x & 63;
  const int half = lane >> 5;
  const int col = lane & 31;
  const int n = (int)((blockIdx.x * blockDim.x + threadIdx.x) >> 6);
  if (n >= N_ENTITY) return;

  float4 accA, accB = make_float4(0.f, 0.f, 0.f, 0.f);
  if (half == 0) {
    uint2 lv = *(const uint2*)(Yl + (size_t)n * 64 + col * 2);
    accA = make_float4(bflo(lv.x), bfhi(lv.x), bflo(lv.y), bfhi(lv.y));
  } else {
    accA = make_float4(0.f, 0.f, 0.f, 0.f);
  }

  unsigned p0 = off0[n], c0t = deg0[n];   // bwd list (src==n): Yb/Zb
  unsigned p1 = off1[n], c1t = deg1[n];   // fwd list (tgt==n): Yf/Zf
  const float r0n = rdeg0[n], r1n = rdeg1[n];

  while (c0t > 0 || c1t > 0) {
    int c0 = (int)((c0t < 64u) ? c0t : 64u);
    int c1 = (int)((c1t < 64u) ? c1t : 64u);
    unsigned d0 = 0, d1 = 0;
    float rw0 = 0.f, rw1 = 0.f;
    if (lane < c0) {
      d0 = el0[p0 + lane];
      rw0 = r0n * rdeg1[d0 >> 10];        // w = rdeg0[n] * rdeg1[tgt]
    }
    if (lane < c1) {
      d1 = el1[p1 + lane];
      rw1 = r1n * rdeg0[d1 >> 10];        // w = rdeg0[src] * rdeg1[n]
    }
    int i0 = 0, i1 = 0;
    while (i0 + 4 <= c0 && i1 + 4 <= c1) {
      int ea0 = i0 + half, ea1 = i0 + 2 + half;
      int eb0 = i1 + half, eb1 = i1 + 2 + half;
      unsigned pka = __shfl(d0, ea0, 64); float wa = __shfl(rw0, ea0, 64);
      unsigned pkb = __shfl(d0, ea1, 64); float wb = __shfl(rw0, ea1, 64);
      unsigned pkc = __shfl(d1, eb0, 64); float wc = __shfl(rw1, eb0, 64);
      unsigned pkd = __shfl(d1, eb1, 64); float wd = __shfl(rw1, eb1, 64);
      unsigned ya = Yb[(size_t)(pka >> 10) * 32 + col];
      unsigned za = Zb[(size_t)(pka & 1023u) * 32 + col];
      unsigned yb = Yb[(size_t)(pkb >> 10) * 32 + col];
      unsigned zb = Zb[(size_t)(pkb & 1023u) * 32 + col];
      unsigned yc = Yf[(size_t)(pkc >> 10) * 32 + col];
      unsigned zc = Zf[(size_t)(pkc & 1023u) * 32 + col];
      unsigned yd = Yf[(size_t)(pkd >> 10) * 32 + col];
      unsigned zd = Zf[(size_t)(pkd & 1023u) * 32 + col];
      f32x2 al = __builtin_amdgcn_cvt_pk_f32_fp8((int)ya, false);
      f32x2 ah = __builtin_amdgcn_cvt_pk_f32_fp8((int)ya, true);
      f32x2 aul = __builtin_amdgcn_cvt_pk_f32_fp8((int)za, false);
      f32x2 auh = __builtin_amdgcn_cvt_pk_f32_fp8((int)za, true);
      f32x2 bl = __builtin_amdgcn_cvt_pk_f32_fp8((int)yb, false);
      f32x2 bh = __builtin_amdgcn_cvt_pk_f32_fp8((int)yb, true);
      f32x2 bul = __builtin_amdgcn_cvt_pk_f32_fp8((int)zb, false);
      f32x2 buh = __builtin_amdgcn_cvt_pk_f32_fp8((int)zb, true);
      f32x2 cl = __builtin_amdgcn_cvt_pk_f32_fp8((int)yc, false);
      f32x2 ch = __builtin_amdgcn_cvt_pk_f32_fp8((int)yc, true);
      f32x2 cul = __builtin_amdgcn_cvt_pk_f32_fp8((int)zc, false);
      f32x2 cuh = __builtin_amdgcn_cvt_pk_f32_fp8((int)zc, true);
      f32x2 dl = __builtin_amdgcn_cvt_pk_f32_fp8((int)yd, false);
      f32x2 dh = __builtin_amdgcn_cvt_pk_f32_fp8((int)yd, true);
      f32x2 dul = __builtin_amdgcn_cvt_pk_f32_fp8((int)zd, false);
      f32x2 duh = __builtin_amdgcn_cvt_pk_f32_fp8((int)zd, true);
      accA.x = fmaf(wa, al.x - aul.x, accA.x);
      accA.y = fmaf(wa, al.y - aul.y, accA.y);
      accA.z = fmaf(wa, ah.x - auh.x, accA.z);
      accA.w = fmaf(wa, ah.y - auh.y, accA.w);
      accB.x = fmaf(wb, bl.x - bul.x, accB.x);
      accB.y = fmaf(wb, bl.y - bul.y, accB.y);
      accB.z = fmaf(wb, bh.x - buh.x, accB.z);
      accB.w = fmaf(wb, bh.y - buh.y, accB.w);
      accA.x = fmaf(wc, cl.x - cul.x, accA.x);
      accA.y = fmaf(wc, cl.y - cul.y, accA.y);
      accA.z = fmaf(wc, ch.x - cuh.x, accA.z);
      accA.w = fmaf(wc, ch.y - cuh.y, accA.w);
      accB.x = fmaf(wd, dl.x - dul.x, accB.x);
      accB.y = fmaf(wd, dl.y - dul.y, accB.y);
      accB.z = fmaf(wd, dh.x - duh.x, accB.z);
      accB.w = fmaf(wd, dh.y - duh.y, accB.w);
      i0 += 4; i1 += 4;
    }
    for (; i0 < c0; i0 += 2) pstep(Yb, Zb, d0, rw0, i0, half, col, accA);
    for (; i1 < c1; i1 += 2) pstep(Yf, Zf, d1, rw1, i1, half, col, accB);
    p0 += (unsigned)c0; c0t -= (unsigned)c0;
    p1 += (unsigned)c1; c1t -= (unsigned)c1;
  }

  accA.x += accB.x; accA.y += accB.y; accA.z += accB.z; accA.w += accB.w;
  accA.x += __shfl_down(accA.x, 32, 64);
  accA.y += __shfl_down(accA.y, 32, 64);
  accA.z += __shfl_down(accA.z, 32, 64);
  accA.w += __shfl_down(accA.w, 32, 64);
  if (half == 0) *(float4*)(out + (size_t)n * D + col * 4) = accA;
}

// ---------------- BN statistics + finalize ----------------
__global__ void k_stats1(const float* __restrict__ out, float* __restrict__ part) {
  const int t = threadIdx.x;  // 128
  float s = 0.f, sq = 0.f;
  for (int r = blockIdx.x; r < N_ENTITY; r += gridDim.x) {
    float v = out[(size_t)r * D + t];
    s += v;
    sq = fmaf(v, v, sq);
  }
  part[blockIdx.x * 256 + t] = s;
  part[blockIdx.x * 256 + 128 + t] = sq;
}

__global__ void k_stats2(const float* __restrict__ part, const float* __restrict__ gamma,
                         const float* __restrict__ beta, float* __restrict__ ksh) {
  const int t = threadIdx.x;  // 128
  float s = 0.f, sq = 0.f;
  for (int b = 0; b < 256; ++b) {
    s += part[b * 256 + t];
    sq += part[b * 256 + 128 + t];
  }
  float mean = s * (1.f / N_ENTITY);
  float var = sq * (1.f / N_ENTITY) - mean * mean;
  float scale = gamma[t] * (1.f / 3.f) * rsqrtf(var * (1.f / 9.f) + BN_EPS);
  ksh[t] = scale;
  ksh[128 + t] = beta[t] - mean * scale;
}

__global__ void k_final(float* __restrict__ out, const float* __restrict__ ksh) {
  const size_t i4 = ((size_t)blockIdx.x * blockDim.x + threadIdx.x) * 4;
  if (i4 >= (size_t)N_ENTITY * D) return;
  const int c = (int)(i4 & 127);
  float4 v = *(float4*)(out + i4);
  v.x = fmaf(v.x, ksh[c + 0], ksh[128 + c + 0]);
  v.y = fmaf(v.y, ksh[c + 1], ksh[128 + c + 1]);
  v.z = fmaf(v.z, ksh[c + 2], ksh[128 + c + 2]);
  v.w = fmaf(v.w, ksh[c + 3], ksh[128 + c + 3]);
  *(float4*)(out + i4) = v;
}

// ---------------- host launcher ----------------
extern "C" void kernel_launch(void* const* d_in, const int* in_sizes, int n_in,
                              void* d_out, int out_size, void* d_ws, size_t ws_size,
                              hipStream_t stream) {
  const float* xe    = (const float*)d_in[0];
  const float* xr    = (const float*)d_in[1];
  const float* wl    = (const float*)d_in[2];
  const float* wf    = (const float*)d_in[3];
  const float* wb    = (const float*)d_in[4];
  const float* wrel  = (const float*)d_in[5];
  const float* sl    = (const float*)d_in[6];
  // d_in[7] = bias: cancels inside BatchNorm, unused
  const float* gamma = (const float*)d_in[8];
  const float* beta  = (const float*)d_in[9];
  const int* eidx    = (const int*)d_in[10];
  const int* etype   = (const int*)d_in[11];
  const int* esrc = eidx;
  const int* etgt = eidx + NE;

  float* outF  = (float*)d_out;
  float* xrnew = (float*)d_out + (size_t)N_ENTITY * D;

  float* wsf = (float*)d_ws;
  unsigned* wsu = (unsigned*)d_ws;
  unsigned* Yf  = wsu + OFF_YF;
  unsigned* Yb  = wsu + OFF_YB;
  unsigned* Yl  = wsu + OFF_YL;
  unsigned* Zf  = wsu + OFF_ZF;
  unsigned* Zb  = wsu + OFF_ZB;
  unsigned* wpk = wsu + OFF_WPK;
  float* wrT = wsf + OFF_WRT;
  float* slw = wsf + OFF_SLW;
  unsigned* deg0 = wsu + OFF_DEG0;
  unsigned* deg1 = wsu + OFF_DEG1;
  unsigned* off0 = wsu + OFF_OFF0;
  unsigned* off1 = wsu + OFF_OFF1;
  float* rdeg0 = wsf + OFF_RDG0;
  float* rdeg1 = wsf + OFF_RDG1;
  unsigned* gcnt = wsu + OFF_GCNT;
  uint2* bin0 = (uint2*)(wsu + OFF_BIN0);
  uint2* bin1 = (uint2*)(wsu + OFF_BIN1);
  unsigned* el0 = wsu + OFF_EL0;
  unsigned* el1 = wsu + OFF_EL1;
  float* part = wsf + OFF_PART;
  float* ksh  = wsf + OFF_KSH;

  hipMemsetAsync(gcnt, 0, 128 * sizeof(unsigned), stream);

  k_prep<<<NB_PREP, 256, 0, stream>>>(wl, wf, wb, wrel, sl, wpk, wrT, slw);

  k_mid<<<NB_BIN + NB_GEMM + NB_XR, 256, 0, stream>>>(
      esrc, etgt, etype, gcnt, bin0, bin1,
      xe, wpk, slw, Yl, Yf, Yb,
      xr, wf, wb, wrT, Zf, Zb, xrnew);

  k_bucket<<<128, 256, 0, stream>>>(bin0, bin1, gcnt, deg0, deg1, off0, off1,
                                    rdeg0, rdeg1, el0, el1);

  k_gather<<<(N_ENTITY * 64 + 255) / 256, 256, 0, stream>>>(
      Yl, Yf, Yb, Zf, Zb, deg0, deg1, off0, off1, rdeg0, rdeg1, el0, el1, outF);

  k_stats1<<<256, 128, 0, stream>>>(outF, part);
  k_stats2<<<1, 128, 0, stream>>>(part, gamma, beta, ksh);
  k_final<<<(N_ENTITY * D / 4 + 255) / 256, 256, 0, stream>>>(outF, ksh);
}

// Round 15
// 184.610 us; speedup vs baseline: 1.1001x; 1.1001x over previous
//
#include <hip/hip_runtime.h>

namespace {

constexpr int N_ENTITY = 50000;
constexpr int NR2      = 1000;     // 2 * num_relations
constexpr int NE       = 600000;
constexpr int D        = 128;
constexpr int BCAP     = 16384;    // coarse-bucket capacity (mean ~12.3K, +36 sigma)
constexpr float BN_EPS = 1e-5f;

constexpr int NB_BIN   = (NE + 2047) / 2048;   // 293 bin blocks
constexpr int NB_PREP  = 89;                   // prep blocks (64 transpose + 1 slw + 24 pack)
constexpr int NB_GEMM  = (N_ENTITY + 63) / 64; // 782 gemm blocks
constexpr int NB_XR    = NR2 / 8;              // 125 xr blocks

// ---- workspace layout (units of 4 bytes) ----
constexpr size_t OFF_YF   = 0;                     // 1,600,000 (fp8 x4 per u32)
constexpr size_t OFF_YB   = OFF_YF + 1600000;      // 1,600,000
constexpr size_t OFF_YL   = OFF_YB + 1600000;      // 3,200,000 (bf16 pairs)
constexpr size_t OFF_ZF   = OFF_YL + 3200000;      // 32,000 (fp8)
constexpr size_t OFF_ZB   = OFF_ZF + 32000;        // 32,000
constexpr size_t OFF_WPK  = OFF_ZB + 32000;        // 24,576
constexpr size_t OFF_WRT  = OFF_WPK + 24576;       // 16,384
constexpr size_t OFF_SLW  = OFF_WRT + 16384;       // 256
constexpr size_t OFF_DEG0 = OFF_SLW + 256;         // 50,048
constexpr size_t OFF_DEG1 = OFF_DEG0 + 50048;      // 50,048
constexpr size_t OFF_OFF0 = OFF_DEG1 + 50048;      // 50,048
constexpr size_t OFF_OFF1 = OFF_OFF0 + 50048;      // 50,048
constexpr size_t OFF_RDG0 = OFF_OFF1 + 50048;      // 50,048 f32
constexpr size_t OFF_RDG1 = OFF_RDG0 + 50048;      // 50,048 f32
constexpr size_t OFF_GCNT = OFF_RDG1 + 50048;      // 128
constexpr size_t OFF_BIN0 = OFF_GCNT + 128;        // 2,097,152 (uint2 x 64x16384)
constexpr size_t OFF_BIN1 = OFF_BIN0 + 2097152;    // 2,097,152
constexpr size_t OFF_EL0  = OFF_BIN1 + 2097152;    // 1,048,576 u32
constexpr size_t OFF_EL1  = OFF_EL0 + 1048576;     // 1,048,576
constexpr size_t OFF_PART = OFF_EL1 + 1048576;     // 65,536
constexpr size_t OFF_KSH  = OFF_PART + 65536;      // 256
// total ~13.16M u32 = 52.7 MB

} // namespace

typedef __attribute__((ext_vector_type(8))) short bf16x8;
typedef __attribute__((ext_vector_type(4))) float f32x4;
typedef __attribute__((ext_vector_type(2))) float f32x2;

__device__ inline unsigned f2bf(float x) {
  unsigned u = __float_as_uint(x);
  return (u + 0x7FFFu + ((u >> 16) & 1u)) >> 16;   // RNE
}
__device__ inline unsigned pack2bf(float a, float b) { return f2bf(a) | (f2bf(b) << 16); }
__device__ inline float bflo(unsigned v) { return __uint_as_float(v << 16); }
__device__ inline float bfhi(unsigned v) { return __uint_as_float(v & 0xFFFF0000u); }

// ---------------- phase 1: coarse binning + (fused) weight prep ----------------
__global__ __launch_bounds__(256) void k_binprep(
    const int* __restrict__ esrc, const int* __restrict__ etgt,
    const int* __restrict__ etype, unsigned* __restrict__ gcnt,
    uint2* __restrict__ bin0, uint2* __restrict__ bin1,
    const float* __restrict__ wl, const float* __restrict__ wf,
    const float* __restrict__ wb, const float* __restrict__ wrel,
    const float* __restrict__ sl,
    unsigned* __restrict__ wpk, float* __restrict__ wrT, float* __restrict__ slw) {
  const int tid = threadIdx.x;
  if (blockIdx.x >= NB_BIN) {
    const int b = blockIdx.x - NB_BIN;
    if (b < 64) {
      int i = b * 256 + tid;
      wrT[(i & 127) * D + (i >> 7)] = wrel[i];
    } else if (b == 64) {
      if (tid < 128) {
        float a = 0.f;
        for (int k = 0; k < D; ++k) a = fmaf(sl[k], wl[k * D + tid], a);
        slw[tid] = a;
      }
    } else {
      int idx = (b - 65) * 256 + tid;   // < 6144
      int w = idx / 2048, rem = idx % 2048;
      int frag = rem / 64, l = rem % 64;
      int ct = frag >> 2, kf = frag & 3;
      const float* W = (w == 0) ? wl : (w == 1) ? wf : wb;
      int krow = kf * 32 + (l >> 4) * 8;
      int col = ct * 16 + (l & 15);
      unsigned base = (unsigned)(w * 8192 + (frag * 64 + l) * 4);
#pragma unroll
      for (int j = 0; j < 8; j += 2) {
        float a = W[(krow + j) * D + col];
        float bb = W[(krow + j + 1) * D + col];
        wpk[base + (j >> 1)] = pack2bf(a, bb);
      }
    }
    return;
  }
  __shared__ unsigned cnt[128], base[128];
  if (tid < 128) cnt[tid] = 0;
  __syncthreads();
  const int start = blockIdx.x * 2048;
  int sv[8], tv[8];
#pragma unroll
  for (int k = 0; k < 8; ++k) {
    int i = start + k * 256 + tid;
    if (i < NE) {
      sv[k] = esrc[i]; tv[k] = etgt[i];
      atomicAdd(&cnt[(unsigned)sv[k] >> 10], 1u);
      atomicAdd(&cnt[64 + ((unsigned)tv[k] >> 10)], 1u);
    } else {
      sv[k] = -1; tv[k] = -1;
    }
  }
  __syncthreads();
  if (tid < 128) {
    base[tid] = atomicAdd(&gcnt[tid], cnt[tid]);
    cnt[tid] = 0;
  }
  __syncthreads();
#pragma unroll
  for (int k = 0; k < 8; ++k) {
    int i = start + k * 256 + tid;
    if (i < NE) {
      int s = sv[k], t = tv[k], et = etype[i];
      unsigned b0 = (unsigned)s >> 10, b1 = (unsigned)t >> 10;
      unsigned r0 = atomicAdd(&cnt[b0], 1u);
      unsigned p0 = base[b0] + r0;
      if (p0 < (unsigned)BCAP)
        bin0[(size_t)b0 * BCAP + p0] =
            make_uint2(((unsigned)s << 16) | (unsigned)t, (unsigned)(2 * et + 1));
      unsigned r1 = atomicAdd(&cnt[64 + b1], 1u);
      unsigned p1 = base[64 + b1] + r1;
      if (p1 < (unsigned)BCAP)
        bin1[(size_t)b1 * BCAP + p1] =
            make_uint2(((unsigned)t << 16) | (unsigned)s, (unsigned)(2 * et));
    }
  }
}

// ---------------- phase 2 (fused): MFMA GEMM + bucket CSR + x_r GEMM ----------------
__global__ __launch_bounds__(256) void k_phase2(
    const float* __restrict__ xe, const unsigned* __restrict__ wpk,
    const float* __restrict__ slw, unsigned* __restrict__ Yl,
    unsigned* __restrict__ Yf, unsigned* __restrict__ Yb,
    const uint2* __restrict__ bin0, const uint2* __restrict__ bin1,
    const unsigned* __restrict__ gcnt,
    unsigned* __restrict__ deg0, unsigned* __restrict__ deg1,
    unsigned* __restrict__ off0, unsigned* __restrict__ off1,
    float* __restrict__ rdeg0, float* __restrict__ rdeg1,
    unsigned* __restrict__ el0, unsigned* __restrict__ el1,
    const float* __restrict__ xr, const float* __restrict__ wf,
    const float* __restrict__ wb, const float* __restrict__ wrT,
    unsigned* __restrict__ Zf, unsigned* __restrict__ Zb, float* __restrict__ xrnew) {
  __shared__ float smem[64 * 140];   // 35.8 KB, shared by all three paths
  const int tid = threadIdx.x;

  if (blockIdx.x < NB_GEMM) {
    const int wv = tid >> 6, l = tid & 63;
    const int tile = blockIdx.x * 64;
    const int arow = tile + wv * 16 + (l & 15);
    const int arc = (arow < N_ENTITY) ? arow : (N_ENTITY - 1);
    const int kbase = (l >> 4) * 8;
    bf16x8 a[4];
#pragma unroll
    for (int kf = 0; kf < 4; ++kf) {
      const float* src = xe + (size_t)arc * D + kf * 32 + kbase;
      float4 lo = *(const float4*)(src);
      float4 hi = *(const float4*)(src + 4);
      union { bf16x8 v; unsigned u[4]; } cv;
      cv.u[0] = pack2bf(lo.x, lo.y);
      cv.u[1] = pack2bf(lo.z, lo.w);
      cv.u[2] = pack2bf(hi.x, hi.y);
      cv.u[3] = pack2bf(hi.z, hi.w);
      a[kf] = cv.v;
    }
    for (int widx = 0; widx < 3; ++widx) {
      const unsigned* wbase = wpk + widx * 8192;
#pragma unroll
      for (int ct = 0; ct < 8; ++ct) {
        f32x4 acc = {0.f, 0.f, 0.f, 0.f};
#pragma unroll
        for (int kf = 0; kf < 4; ++kf) {
          const bf16x8 b = *(const bf16x8*)(wbase + ((ct * 4 + kf) * 64 + l) * 4);
          acc = __builtin_amdgcn_mfma_f32_16x16x32_bf16(a[kf], b, acc, 0, 0, 0);
        }
        const int rbase = wv * 16 + (l >> 4) * 4;
        const int cc = ct * 16 + (l & 15);
#pragma unroll
        for (int j = 0; j < 4; ++j) smem[(rbase + j) * 140 + cc] = acc[j];
      }
      __syncthreads();
      for (int f = tid; f < 64 * 32; f += 256) {
        int row = f >> 5, c4 = (f & 31) * 4;
        int g = tile + row;
        if (g < N_ENTITY) {
          float4 v = *(float4*)(smem + row * 140 + c4);
          if (widx == 0) {
            float4 s = *(const float4*)(slw + c4);
            uint2 p = make_uint2(pack2bf(v.x - s.x, v.y - s.y),
                                 pack2bf(v.z - s.z, v.w - s.w));
            *(uint2*)(Yl + (size_t)g * 64 + (c4 >> 1)) = p;
          } else {
            int p = __builtin_amdgcn_cvt_pk_fp8_f32(v.x, v.y, 0, false);
            p = __builtin_amdgcn_cvt_pk_fp8_f32(v.z, v.w, p, true);
            unsigned* dst = ((widx == 1) ? Yf : Yb);
            dst[(size_t)g * 32 + (c4 >> 2)] = (unsigned)p;
          }
        }
      }
      __syncthreads();
    }
    return;
  }

  if (blockIdx.x < NB_GEMM + 128) {
    unsigned* hist = (unsigned*)smem;
    unsigned* excl = hist + 1024;
    unsigned* wtot = excl + 1024;
    unsigned* wof  = wtot + 4;
    const int bb = (blockIdx.x - NB_GEMM) & 63, dd = (blockIdx.x - NB_GEMM) >> 6;
    const uint2* bin = dd ? bin1 : bin0;
    unsigned* deg = dd ? deg1 : deg0;
    unsigned* off = dd ? off1 : off0;
    float* rdeg = dd ? rdeg1 : rdeg0;
    unsigned* el = dd ? el1 : el0;
    const int n0 = bb << 10;
    unsigned m = gcnt[dd * 64 + bb];
    if (m > (unsigned)BCAP) m = (unsigned)BCAP;
    const uint2* src = bin + (size_t)bb * BCAP;

#pragma unroll
    for (int k = 0; k < 4; ++k) hist[tid * 4 + k] = 0;
    __syncthreads();
    for (unsigned j = tid; j < m; j += 256) {
      unsigned n = src[j].x >> 16;
      atomicAdd(&hist[n - n0], 1u);
    }
    __syncthreads();
    unsigned h0 = hist[tid * 4], h1 = hist[tid * 4 + 1];
    unsigned h2 = hist[tid * 4 + 2], h3 = hist[tid * 4 + 3];
    unsigned ts = h0 + h1 + h2 + h3;
    unsigned incl = ts;
    const int lane = tid & 63, wid = tid >> 6;
#pragma unroll
    for (int dsh = 1; dsh < 64; dsh <<= 1) {
      unsigned nv = __shfl_up(incl, dsh, 64);
      if (lane >= dsh) incl += nv;
    }
    if (lane == 63) wtot[wid] = incl;
    __syncthreads();
    if (tid == 0) {
      unsigned a = 0;
      for (int w = 0; w < 4; ++w) { wof[w] = a; a += wtot[w]; }
    }
    __syncthreads();
    unsigned ex = wof[wid] + incl - ts;
    excl[tid * 4] = ex;
    excl[tid * 4 + 1] = ex + h0;
    excl[tid * 4 + 2] = ex + h0 + h1;
    excl[tid * 4 + 3] = ex + h0 + h1 + h2;
    const unsigned bstart = (unsigned)bb * BCAP;
#pragma unroll
    for (int k = 0; k < 4; ++k) {
      int idx = tid * 4 + k;
      int n = n0 + idx;
      if (n < N_ENTITY) {
        unsigned dv = hist[idx];
        deg[n] = dv;
        off[n] = bstart + excl[idx];
        rdeg[n] = rsqrtf((float)dv);
      }
    }
    __syncthreads();
#pragma unroll
    for (int k = 0; k < 4; ++k) hist[tid * 4 + k] = 0;
    __syncthreads();
    for (unsigned j = tid; j < m; j += 256) {
      uint2 e = src[j];
      unsigned li = (e.x >> 16) - (unsigned)n0;
      unsigned other = e.x & 0xFFFFu;
      unsigned r = atomicAdd(&hist[li], 1u);
      el[bstart + excl[li] + r] = (other << 10) | e.y;
    }
    return;
  }

  // ---- x_r @ {w_fwd, w_bwd, w_rel^T}: Zf/Zb fp8, xrnew f32 ----
  float* xs = smem;
  const int tile = (blockIdx.x - NB_GEMM - 128) * 8;
  for (int f = tid * 4; f < 8 * 128; f += 1024) {
    int rr = f >> 7, kk = f & 127;
    *(float4*)(xs + rr * 132 + kk) = *(const float4*)(xr + (size_t)(tile + rr) * D + kk);
  }
  __syncthreads();
  const int c4 = (tid & 31) * 4;
  const int rs = tid >> 5;
  const int row = tile + rs;
  float4 af = make_float4(0, 0, 0, 0), ab = make_float4(0, 0, 0, 0), ar = make_float4(0, 0, 0, 0);
#pragma unroll 4
  for (int k = 0; k < 128; ++k) {
    float x = xs[rs * 132 + k];
    float4 f4 = *(const float4*)(wf + k * D + c4);
    float4 b4 = *(const float4*)(wb + k * D + c4);
    float4 r4 = *(const float4*)(wrT + k * D + c4);
    af.x = fmaf(x, f4.x, af.x); af.y = fmaf(x, f4.y, af.y);
    af.z = fmaf(x, f4.z, af.z); af.w = fmaf(x, f4.w, af.w);
    ab.x = fmaf(x, b4.x, ab.x); ab.y = fmaf(x, b4.y, ab.y);
    ab.z = fmaf(x, b4.z, ab.z); ab.w = fmaf(x, b4.w, ab.w);
    ar.x = fmaf(x, r4.x, ar.x); ar.y = fmaf(x, r4.y, ar.y);
    ar.z = fmaf(x, r4.z, ar.z); ar.w = fmaf(x, r4.w, ar.w);
  }
  int pf = __builtin_amdgcn_cvt_pk_fp8_f32(af.x, af.y, 0, false);
  pf = __builtin_amdgcn_cvt_pk_fp8_f32(af.z, af.w, pf, true);
  int pb = __builtin_amdgcn_cvt_pk_fp8_f32(ab.x, ab.y, 0, false);
  pb = __builtin_amdgcn_cvt_pk_fp8_f32(ab.z, ab.w, pb, true);
  Zf[(size_t)row * 32 + (c4 >> 2)] = (unsigned)pf;
  Zb[(size_t)row * 32 + (c4 >> 2)] = (unsigned)pb;
  *(float4*)(xrnew + (size_t)row * D + c4) = ar;
}

// ---------------- per-entity edge aggregation (fp8 messages) ----------------
__device__ inline void edge1(const unsigned short* __restrict__ Y,
                             const unsigned short* __restrict__ Z,
                             unsigned dx, float rw, int i, int lane, float2& acc) {
  unsigned pk = __shfl(dx, i, 64);
  float w = __shfl(rw, i, 64);
  f32x2 yv = __builtin_amdgcn_cvt_pk_f32_fp8((int)Y[(size_t)(pk >> 10) * 64 + lane], false);
  f32x2 zv = __builtin_amdgcn_cvt_pk_f32_fp8((int)Z[(size_t)(pk & 1023u) * 64 + lane], false);
  acc.x = fmaf(w, yv.x - zv.x, acc.x);
  acc.y = fmaf(w, yv.y - zv.y, acc.y);
}

__device__ inline void drain4(const unsigned short* __restrict__ Y,
                              const unsigned short* __restrict__ Z,
                              unsigned dx, float rw, int& i, int c, int lane,
                              float2& accA, float2& accB) {
  for (; i + 4 <= c; i += 4) {
    unsigned pk0 = __shfl(dx, i, 64);     float w0 = __shfl(rw, i, 64);
    unsigned pk1 = __shfl(dx, i + 1, 64); float w1 = __shfl(rw, i + 1, 64);
    unsigned pk2 = __shfl(dx, i + 2, 64); float w2 = __shfl(rw, i + 2, 64);
    unsigned pk3 = __shfl(dx, i + 3, 64); float w3 = __shfl(rw, i + 3, 64);
    int y0 = Y[(size_t)(pk0 >> 10) * 64 + lane];
    int z0 = Z[(size_t)(pk0 & 1023u) * 64 + lane];
    int y1 = Y[(size_t)(pk1 >> 10) * 64 + lane];
    int z1 = Z[(size_t)(pk1 & 1023u) * 64 + lane];
    int y2 = Y[(size_t)(pk2 >> 10) * 64 + lane];
    int z2 = Z[(size_t)(pk2 & 1023u) * 64 + lane];
    int y3 = Y[(size_t)(pk3 >> 10) * 64 + lane];
    int z3 = Z[(size_t)(pk3 & 1023u) * 64 + lane];
    f32x2 a0 = __builtin_amdgcn_cvt_pk_f32_fp8(y0, false);
    f32x2 b0 = __builtin_amdgcn_cvt_pk_f32_fp8(z0, false);
    f32x2 a1 = __builtin_amdgcn_cvt_pk_f32_fp8(y1, false);
    f32x2 b1 = __builtin_amdgcn_cvt_pk_f32_fp8(z1, false);
    f32x2 a2 = __builtin_amdgcn_cvt_pk_f32_fp8(y2, false);
    f32x2 b2 = __builtin_amdgcn_cvt_pk_f32_fp8(z2, false);
    f32x2 a3 = __builtin_amdgcn_cvt_pk_f32_fp8(y3, false);
    f32x2 b3 = __builtin_amdgcn_cvt_pk_f32_fp8(z3, false);
    accA.x = fmaf(w0, a0.x - b0.x, accA.x);
    accA.y = fmaf(w0, a0.y - b0.y, accA.y);
    accB.x = fmaf(w1, a1.x - b1.x, accB.x);
    accB.y = fmaf(w1, a1.y - b1.y, accB.y);
    accA.x = fmaf(w2, a2.x - b2.x, accA.x);
    accA.y = fmaf(w2, a2.y - b2.y, accA.y);
    accB.x = fmaf(w3, a3.x - b3.x, accB.x);
    accB.y = fmaf(w3, a3.y - b3.y, accB.y);
  }
}

__global__ __launch_bounds__(256) void k_gather(
    const unsigned* __restrict__ Yl,
    const unsigned short* __restrict__ Yf, const unsigned short* __restrict__ Yb,
    const unsigned short* __restrict__ Zf, const unsigned short* __restrict__ Zb,
    const unsigned* __restrict__ deg0, const unsigned* __restrict__ deg1,
    const unsigned* __restrict__ off0, const unsigned* __restrict__ off1,
    const float* __restrict__ rdeg0, const float* __restrict__ rdeg1,
    const unsigned* __restrict__ el0, const unsigned* __restrict__ el1,
    float* __restrict__ out) {
  const int lane = threadIdx.x & 63;
  const int n = (int)((blockIdx.x * blockDim.x + threadIdx.x) >> 6);
  if (n >= N_ENTITY) return;
  const unsigned lv = Yl[(size_t)n * 64 + lane];
  float2 accA = make_float2(bflo(lv), bfhi(lv));   // loop term (slw pre-subtracted, bf16)
  float2 accB = make_float2(0.f, 0.f);

  unsigned p0 = off0[n], q0 = p0 + deg0[n];   // bwd list (src==n): Yb/Zb
  unsigned p1 = off1[n], q1 = p1 + deg1[n];   // fwd list (tgt==n): Yf/Zf
  const float r0n = rdeg0[n], r1n = rdeg1[n];

  while (p0 < q0 || p1 < q1) {
    int c0 = (int)((q0 - p0 < 64u) ? (q0 - p0) : 64u);
    int c1 = (int)((q1 - p1 < 64u) ? (q1 - p1) : 64u);
    unsigned d0 = 0, d1 = 0;
    float rw0 = 0.f, rw1 = 0.f;
    if (lane < c0) {
      d0 = el0[p0 + lane];
      rw0 = r0n * rdeg1[d0 >> 10];            // w = rdeg0[n] * rdeg1[tgt]
    }
    if (lane < c1) {
      d1 = el1[p1 + lane];
      rw1 = r1n * rdeg0[d1 >> 10];            // w = rdeg0[src] * rdeg1[n]
    }
    int i0 = 0, i1 = 0;
    while (i0 + 4 <= c0 && i1 + 4 <= c1) {
      unsigned a0 = __shfl(d0, i0, 64);     float wa0 = __shfl(rw0, i0, 64);
      unsigned a1 = __shfl(d0, i0 + 1, 64); float wa1 = __shfl(rw0, i0 + 1, 64);
      unsigned a2 = __shfl(d0, i0 + 2, 64); float wa2 = __shfl(rw0, i0 + 2, 64);
      unsigned a3 = __shfl(d0, i0 + 3, 64); float wa3 = __shfl(rw0, i0 + 3, 64);
      unsigned b0 = __shfl(d1, i1, 64);     float wb0 = __shfl(rw1, i1, 64);
      unsigned b1 = __shfl(d1, i1 + 1, 64); float wb1 = __shfl(rw1, i1 + 1, 64);
      unsigned b2 = __shfl(d1, i1 + 2, 64); float wb2 = __shfl(rw1, i1 + 2, 64);
      unsigned b3 = __shfl(d1, i1 + 3, 64); float wb3 = __shfl(rw1, i1 + 3, 64);
      int ya0 = Yb[(size_t)(a0 >> 10) * 64 + lane];
      int za0 = Zb[(size_t)(a0 & 1023u) * 64 + lane];
      int ya1 = Yb[(size_t)(a1 >> 10) * 64 + lane];
      int za1 = Zb[(size_t)(a1 & 1023u) * 64 + lane];
      int ya2 = Yb[(size_t)(a2 >> 10) * 64 + lane];
      int za2 = Zb[(size_t)(a2 & 1023u) * 64 + lane];
      int ya3 = Yb[(size_t)(a3 >> 10) * 64 + lane];
      int za3 = Zb[(size_t)(a3 & 1023u) * 64 + lane];
      int yb0 = Yf[(size_t)(b0 >> 10) * 64 + lane];
      int zb0 = Zf[(size_t)(b0 & 1023u) * 64 + lane];
      int yb1 = Yf[(size_t)(b1 >> 10) * 64 + lane];
      int zb1 = Zf[(size_t)(b1 & 1023u) * 64 + lane];
      int yb2 = Yf[(size_t)(b2 >> 10) * 64 + lane];
      int zb2 = Zf[(size_t)(b2 & 1023u) * 64 + lane];
      int yb3 = Yf[(size_t)(b3 >> 10) * 64 + lane];
      int zb3 = Zf[(size_t)(b3 & 1023u) * 64 + lane];
      f32x2 va0 = __builtin_amdgcn_cvt_pk_f32_fp8(ya0, false);
      f32x2 ua0 = __builtin_amdgcn_cvt_pk_f32_fp8(za0, false);
      f32x2 va1 = __builtin_amdgcn_cvt_pk_f32_fp8(ya1, false);
      f32x2 ua1 = __builtin_amdgcn_cvt_pk_f32_fp8(za1, false);
      f32x2 va2 = __builtin_amdgcn_cvt_pk_f32_fp8(ya2, false);
      f32x2 ua2 = __builtin_amdgcn_cvt_pk_f32_fp8(za2, false);
      f32x2 va3 = __builtin_amdgcn_cvt_pk_f32_fp8(ya3, false);
      f32x2 ua3 = __builtin_amdgcn_cvt_pk_f32_fp8(za3, false);
      f32x2 vb0 = __builtin_amdgcn_cvt_pk_f32_fp8(yb0, false);
      f32x2 ub0 = __builtin_amdgcn_cvt_pk_f32_fp8(zb0, false);
      f32x2 vb1 = __builtin_amdgcn_cvt_pk_f32_fp8(yb1, false);
      f32x2 ub1 = __builtin_amdgcn_cvt_pk_f32_fp8(zb1, false);
      f32x2 vb2 = __builtin_amdgcn_cvt_pk_f32_fp8(yb2, false);
      f32x2 ub2 = __builtin_amdgcn_cvt_pk_f32_fp8(zb2, false);
      f32x2 vb3 = __builtin_amdgcn_cvt_pk_f32_fp8(yb3, false);
      f32x2 ub3 = __builtin_amdgcn_cvt_pk_f32_fp8(zb3, false);
      accA.x = fmaf(wa0, va0.x - ua0.x, accA.x);
      accA.y = fmaf(wa0, va0.y - ua0.y, accA.y);
      accB.x = fmaf(wa1, va1.x - ua1.x, accB.x);
      accB.y = fmaf(wa1, va1.y - ua1.y, accB.y);
      accA.x = fmaf(wa2, va2.x - ua2.x, accA.x);
      accA.y = fmaf(wa2, va2.y - ua2.y, accA.y);
      accB.x = fmaf(wa3, va3.x - ua3.x, accB.x);
      accB.y = fmaf(wa3, va3.y - ua3.y, accB.y);
      accA.x = fmaf(wb0, vb0.x - ub0.x, accA.x);
      accA.y = fmaf(wb0, vb0.y - ub0.y, accA.y);
      accB.x = fmaf(wb1, vb1.x - ub1.x, accB.x);
      accB.y = fmaf(wb1, vb1.y - ub1.y, accB.y);
      accA.x = fmaf(wb2, vb2.x - ub2.x, accA.x);
      accA.y = fmaf(wb2, vb2.y - ub2.y, accA.y);
      accB.x = fmaf(wb3, vb3.x - ub3.x, accB.x);
      accB.y = fmaf(wb3, vb3.y - ub3.y, accB.y);
      i0 += 4; i1 += 4;
    }
    drain4(Yb, Zb, d0, rw0, i0, c0, lane, accA, accB);
    for (; i0 < c0; ++i0) edge1(Yb, Zb, d0, rw0, i0, lane, accA);
    drain4(Yf, Zf, d1, rw1, i1, c1, lane, accA, accB);
    for (; i1 < c1; ++i1) edge1(Yf, Zf, d1, rw1, i1, lane, accB);
    p0 += (unsigned)c0;
    p1 += (unsigned)c1;
  }

  accA.x += accB.x;
  accA.y += accB.y;
  *(float2*)(out + (size_t)n * D + lane * 2) = accA;
}

// ---------------- BN statistics + finalize ----------------
__global__ void k_stats1(const float* __restrict__ out, float* __restrict__ part) {
  const int t = threadIdx.x;  // 128
  float s = 0.f, sq = 0.f;
  for (int r = blockIdx.x; r < N_ENTITY; r += gridDim.x) {
    float v = out[(size_t)r * D + t];
    s += v;
    sq = fmaf(v, v, sq);
  }
  part[blockIdx.x * 256 + t] = s;
  part[blockIdx.x * 256 + 128 + t] = sq;
}

__global__ void k_stats2(const float* __restrict__ part, const float* __restrict__ gamma,
                         const float* __restrict__ beta, float* __restrict__ ksh) {
  const int t = threadIdx.x;  // 128
  float s = 0.f, sq = 0.f;
  for (int b = 0; b < 256; ++b) {
    s += part[b * 256 + t];
    sq += part[b * 256 + 128 + t];
  }
  float mean = s * (1.f / N_ENTITY);
  float var = sq * (1.f / N_ENTITY) - mean * mean;
  float scale = gamma[t] * (1.f / 3.f) * rsqrtf(var * (1.f / 9.f) + BN_EPS);
  ksh[t] = scale;
  ksh[128 + t] = beta[t] - mean * scale;
}

__global__ void k_final(float* __restrict__ out, const float* __restrict__ ksh) {
  const size_t i4 = ((size_t)blockIdx.x * blockDim.x + threadIdx.x) * 4;
  if (i4 >= (size_t)N_ENTITY * D) return;
  const int c = (int)(i4 & 127);
  float4 v = *(float4*)(out + i4);
  v.x = fmaf(v.x, ksh[c + 0], ksh[128 + c + 0]);
  v.y = fmaf(v.y, ksh[c + 1], ksh[128 + c + 1]);
  v.z = fmaf(v.z, ksh[c + 2], ksh[128 + c + 2]);
  v.w = fmaf(v.w, ksh[c + 3], ksh[128 + c + 3]);
  *(float4*)(out + i4) = v;
}

// ---------------- host launcher ----------------
extern "C" void kernel_launch(void* const* d_in, const int* in_sizes, int n_in,
                              void* d_out, int out_size, void* d_ws, size_t ws_size,
                              hipStream_t stream) {
  const float* xe    = (const float*)d_in[0];
  const float* xr    = (const float*)d_in[1];
  const float* wl    = (const float*)d_in[2];
  const float* wf    = (const float*)d_in[3];
  const float* wb    = (const float*)d_in[4];
  const float* wrel  = (const float*)d_in[5];
  const float* sl    = (const float*)d_in[6];
  // d_in[7] = bias: cancels inside BatchNorm, unused
  const float* gamma = (const float*)d_in[8];
  const float* beta  = (const float*)d_in[9];
  const int* eidx    = (const int*)d_in[10];
  const int* etype   = (const int*)d_in[11];
  const int* esrc = eidx;
  const int* etgt = eidx + NE;

  float* outF  = (float*)d_out;
  float* xrnew = (float*)d_out + (size_t)N_ENTITY * D;

  float* wsf = (float*)d_ws;
  unsigned* wsu = (unsigned*)d_ws;
  unsigned* Yf  = wsu + OFF_YF;
  unsigned* Yb  = wsu + OFF_YB;
  unsigned* Yl  = wsu + OFF_YL;
  unsigned* Zf  = wsu + OFF_ZF;
  unsigned* Zb  = wsu + OFF_ZB;
  unsigned* wpk = wsu + OFF_WPK;
  float* wrT = wsf + OFF_WRT;
  float* slw = wsf + OFF_SLW;
  unsigned* deg0 = wsu + OFF_DEG0;
  unsigned* deg1 = wsu + OFF_DEG1;
  unsigned* off0 = wsu + OFF_OFF0;
  unsigned* off1 = wsu + OFF_OFF1;
  float* rdeg0 = wsf + OFF_RDG0;
  float* rdeg1 = wsf + OFF_RDG1;
  unsigned* gcnt = wsu + OFF_GCNT;
  uint2* bin0 = (uint2*)(wsu + OFF_BIN0);
  uint2* bin1 = (uint2*)(wsu + OFF_BIN1);
  unsigned* el0 = wsu + OFF_EL0;
  unsigned* el1 = wsu + OFF_EL1;
  float* part = wsf + OFF_PART;
  float* ksh  = wsf + OFF_KSH;

  hipMemsetAsync(gcnt, 0, 128 * sizeof(unsigned), stream);

  k_binprep<<<NB_BIN + NB_PREP, 256, 0, stream>>>(
      esrc, etgt, etype, gcnt, bin0, bin1, wl, wf, wb, wrel, sl, wpk, wrT, slw);

  k_phase2<<<NB_GEMM + 128 + NB_XR, 256, 0, stream>>>(
      xe, wpk, slw, Yl, Yf, Yb,
      bin0, bin1, gcnt, deg0, deg1, off0, off1, rdeg0, rdeg1, el0, el1,
      xr, wf, wb, wrT, Zf, Zb, xrnew);

  k_gather<<<(N_ENTITY * 64 + 255) / 256, 256, 0, stream>>>(
      Yl, (const unsigned short*)Yf, (const unsigned short*)Yb,
      (const unsigned short*)Zf, (const unsigned short*)Zb,
      deg0, deg1, off0, off1, rdeg0, rdeg1, el0, el1, outF);

  k_stats1<<<256, 128, 0, stream>>>(outF, part);
  k_stats2<<<1, 128, 0, stream>>>(part, gamma, beta, ksh);
  k_final<<<(N_ENTITY * D / 4 + 255) / 256, 256, 0, stream>>>(outF, ksh);
}